// Round 9
// baseline (14.899 us; speedup 1.0000x reference)
//
#include <hip/hip_runtime.h>

// Exponential concordance loss — single kernel, 4-chunks-per-block:
// loss_sum = sum over (a,b) with dur[b] < dur[a] and ev[b]==1 of exp(p[a]-p[b])
//          = sum_b w[b] * S_b,  w[b]=ev[b]?exp(-p[b]):0,
//   S_b = sum of exp(p[a]) over rows a with dur_a > dur_b.
// Each of the block's 4 waves register-bitonic-sorts its OWN 64-row chunk and
// publishes (sorted durs, suffix sums of exp(p)) to LDS. Each thread then
// resolves its NB columns against all 4 chunks (one column load + one exp
// amortized over 4 chunks -> 4x fewer transcendentals than R8). 128 blocks.
// Combine: packed 8B relaxed agent store to distinct slots + vmcnt drain +
// relaxed ticket; last block reduces 128 partials in fixed order (determin-
// istic) and resets the module-global ticket (load-time zeroed, not in d_ws).

#define TPB 256
#define NB 8          // columns per thread
#define ACHUNK 64     // rows per chunk == one wave
#define WPB 4         // waves (= chunks) per block

__device__ int g_ticket = 0;

union PackSC {
    struct { float s; int c; } sc;
    unsigned long long u;
};

__global__ void __launch_bounds__(TPB) pair_single(const float* __restrict__ preds,
                                                   const float2* __restrict__ targets, // (dur, ev)
                                                   unsigned long long* __restrict__ partials,
                                                   float* __restrict__ out,
                                                   int n, int nblocks) {
    const int colGroups = n / (TPB * NB);          // 8192/2048 = 4
    const int cg  = blockIdx.x % colGroups;
    const int acg = blockIdx.x / colGroups;        // 0..31 chunk-group
    const int wid  = threadIdx.x >> 6;             // 0..3
    const int lane = threadIdx.x & 63;
    const int base_a = (acg * WPB + wid) * ACHUNK;
    const int base_b = cg * TPB * NB + threadIdx.x;

    __shared__ float sdur[WPB][ACHUNK];            // sorted durations (ascending)
    __shared__ float ssuf[WPB][ACHUNK + 1];        // suffix sums of epos; [64]=0

    // ---- every wave: load its chunk, bitonic sort by dur, suffix-scan epos ----
    {
        float2 t  = targets[base_a + lane];
        float dur = t.x;
        float ep  = __expf(preds[base_a + lane]);
#pragma unroll
        for (int k = 2; k <= 64; k <<= 1) {
#pragma unroll
            for (int j = k >> 1; j > 0; j >>= 1) {
                float od = __shfl_xor(dur, j, 64);
                float oe = __shfl_xor(ep,  j, 64);
                bool lower    = (lane & j) == 0;
                bool asc      = (lane & k) == 0;   // k=64: all ascending
                bool take_min = (lower == asc);
                bool take_other = take_min ? (od < dur) : (od > dur);
                dur = take_other ? od : dur;
                ep  = take_other ? oe : ep;
            }
        }
        float suf = ep;                            // inclusive suffix sum
#pragma unroll
        for (int d = 1; d < 64; d <<= 1) {
            float v = __shfl_down(suf, d, 64);
            suf += (lane + d < 64) ? v : 0.0f;
        }
        sdur[wid][lane] = dur;
        ssuf[wid][lane] = suf;
        if (lane == 0) ssuf[wid][ACHUNK] = 0.0f;
    }

    // ---- all threads: load columns once (coalesced), exp once ----
    float qb[NB], wb[NB];
#pragma unroll
    for (int k = 0; k < NB; ++k) {
        int b = base_b + k * TPB;
        float2 t = targets[b];
        float  p = preds[b];
        qb[k] = t.x;
        wb[k] = (t.y == 1.0f) ? __expf(-p) : 0.0f;
    }
    __syncthreads();

    // ---- per column: search all 4 chunks (amortize column load/exp) ----
    float lsum = 0.0f;
    int   lcnt = 0;
#pragma unroll
    for (int k = 0; k < NB; ++k) {
        if (wb[k] > 0.0f) {                        // ev[b]==1 <=> w_b>0
            float csum = 0.0f;
            int   ccnt = 0;
#pragma unroll
            for (int c = 0; c < WPB; ++c) {
                int pos = 0;                       // count of dur_a <= q
#pragma unroll
                for (int s = 32; s > 0; s >>= 1)
                    pos += (sdur[c][pos + s - 1] <= qb[k]) ? s : 0;
                csum += ssuf[c][pos];
                ccnt += (ACHUNK - pos);
            }
            lsum += wb[k] * csum;
            lcnt += ccnt;
        }
    }

    // ---- wave shuffle-reduce, then cross-wave combine ----
#pragma unroll
    for (int d = 32; d > 0; d >>= 1) {
        lsum += __shfl_down(lsum, d, 64);
        lcnt += __shfl_down(lcnt, d, 64);
    }
    __shared__ float wsum[WPB];
    __shared__ int   wcnt[WPB];
    if (lane == 0) { wsum[wid] = lsum; wcnt[wid] = lcnt; }
    __syncthreads();

    // ---- publish packed partial, drain, relaxed ticket ----
    __shared__ int isLast;
    if (threadIdx.x == 0) {
        PackSC pk;
        pk.sc.s = (wsum[0] + wsum[1]) + (wsum[2] + wsum[3]);
        pk.sc.c = wcnt[0] + wcnt[1] + wcnt[2] + wcnt[3];
        __hip_atomic_store(&partials[blockIdx.x], pk.u,
                           __ATOMIC_RELAXED, __HIP_MEMORY_SCOPE_AGENT);
        asm volatile("s_waitcnt vmcnt(0)" ::: "memory");  // store ack'd at coherence point
        int t = __hip_atomic_fetch_add(&g_ticket, 1,
                                       __ATOMIC_RELAXED, __HIP_MEMORY_SCOPE_AGENT);
        isLast = (t == nblocks - 1);
    }
    __syncthreads();
    if (!isLast) return;

    // ---- last block: reduce all partials in fixed order ----
    __shared__ double    ds[TPB];
    __shared__ long long dc[TPB];
    double    ls = 0.0;
    long long lc = 0;
    for (int i = threadIdx.x; i < nblocks; i += TPB) {
        PackSC pk;
        pk.u = __hip_atomic_load(&partials[i], __ATOMIC_RELAXED, __HIP_MEMORY_SCOPE_AGENT);
        ls += (double)pk.sc.s;
        lc += (long long)pk.sc.c;
    }
    ds[threadIdx.x] = ls;
    dc[threadIdx.x] = lc;
    __syncthreads();
    for (int s = TPB / 2; s > 0; s >>= 1) {
        if (threadIdx.x < s) {
            ds[threadIdx.x] += ds[threadIdx.x + s];
            dc[threadIdx.x] += dc[threadIdx.x + s];
        }
        __syncthreads();
    }
    if (threadIdx.x == 0) {
        out[0] = (dc[0] > 0) ? (float)(ds[0] / (double)dc[0]) : 0.0f;
        // reset ticket for the next call (all blocks of this call have arrived)
        __hip_atomic_store(&g_ticket, 0, __ATOMIC_RELAXED, __HIP_MEMORY_SCOPE_AGENT);
    }
}

extern "C" void kernel_launch(void* const* d_in, const int* in_sizes, int n_in,
                              void* d_out, int out_size, void* d_ws, size_t ws_size,
                              hipStream_t stream) {
    const float*  preds   = (const float*)d_in[0];
    const float2* targets = (const float2*)d_in[1];   // [n] of (dur, ev)
    float* out = (float*)d_out;
    int n = in_sizes[0];   // 8192

    int colGroups   = n / (TPB * NB);              // 4
    int chunkGroups = n / (ACHUNK * WPB);          // 32
    int nblocks     = colGroups * chunkGroups;     // 128

    // ws layout: partials[nblocks] packed (float,int)
    unsigned long long* partials = (unsigned long long*)d_ws;

    pair_single<<<nblocks, TPB, 0, stream>>>(preds, targets, partials, out, n, nblocks);
}

// Round 10
// 13.077 us; speedup vs baseline: 1.1393x; 1.1393x over previous
//
#include <hip/hip_runtime.h>

// Exponential concordance loss — sorted-chunk + suffix-sum + binary search,
// two-kernel structure (in-kernel grid sync proved slower in R4-R7/R9).
// loss_sum = sum over (a,b) with dur[b] < dur[a] and ev[b]==1 of exp(p[a]-p[b])
//          = sum_b w[b] * S_b,  w[b]=ev[b]?exp(-p[b]):0,
//   S_b = sum of exp(p[a]) over rows a with dur_a > dur_b.
// Per 64-row chunk: wave0 bitonic-sorts (dur, epos) by dur across 64 lanes,
// suffix-scans epos, publishes sdur[64]/ssuf[65] to LDS (overlaps with other
// waves' column loads). Each thread resolves NB=4 columns via 6-step binary
// search + suffix lookup. Reduction: wave shuffle (6 steps, no barriers) +
// 4-way cross-wave combine. 1024 blocks (4/CU) shortens per-thread path.

#define TPB 256
#define NB 4          // columns per thread
#define ACHUNK 64     // rows per chunk == one wave

__global__ void __launch_bounds__(TPB) pair_fused(const float* __restrict__ preds,
                                                  const float2* __restrict__ targets, // (dur, ev)
                                                  float* __restrict__ psum,
                                                  int* __restrict__ pcnt,
                                                  int n) {
    const int colGroups = n / (TPB * NB);          // 8192/1024 = 8
    const int cg = blockIdx.x % colGroups;
    const int ac = blockIdx.x / colGroups;
    const int base_a = ac * ACHUNK;
    const int base_b = cg * TPB * NB + threadIdx.x;
    const int wid  = threadIdx.x >> 6;             // 0..3
    const int lane = threadIdx.x & 63;

    __shared__ float sdur[ACHUNK];     // sorted durations (ascending)
    __shared__ float ssuf[ACHUNK + 1]; // inclusive suffix sums of epos; [64]=0

    // ---- wave 0: load chunk, bitonic sort by dur, suffix-scan epos ----
    if (wid == 0) {
        float2 t  = targets[base_a + lane];
        float dur = t.x;
        float ep  = __expf(preds[base_a + lane]);
#pragma unroll
        for (int k = 2; k <= 64; k <<= 1) {
#pragma unroll
            for (int j = k >> 1; j > 0; j >>= 1) {
                float od = __shfl_xor(dur, j, 64);
                float oe = __shfl_xor(ep,  j, 64);
                bool lower    = (lane & j) == 0;
                bool asc      = (lane & k) == 0;   // k=64: all ascending
                bool take_min = (lower == asc);
                bool take_other = take_min ? (od < dur) : (od > dur);
                dur = take_other ? od : dur;
                ep  = take_other ? oe : ep;
            }
        }
        float suf = ep;                            // inclusive suffix sum
#pragma unroll
        for (int d = 1; d < 64; d <<= 1) {
            float v = __shfl_down(suf, d, 64);
            suf += (lane + d < 64) ? v : 0.0f;
        }
        sdur[lane] = dur;
        ssuf[lane] = suf;
        if (lane == 0) ssuf[ACHUNK] = 0.0f;
    }

    // ---- all threads: load columns (coalesced; overlaps wave0's sort) ----
    float qb[NB], wb[NB];
#pragma unroll
    for (int k = 0; k < NB; ++k) {
        int b = base_b + k * TPB;
        float2 t = targets[b];
        float  p = preds[b];
        qb[k] = t.x;
        wb[k] = (t.y == 1.0f) ? __expf(-p) : 0.0f;
    }
    __syncthreads();

    // ---- per column: upper-bound binary search + suffix lookup ----
    float lsum = 0.0f;
    int   lcnt = 0;
#pragma unroll
    for (int k = 0; k < NB; ++k) {
        int pos = 0;                               // count of dur_a <= q
#pragma unroll
        for (int s = 32; s > 0; s >>= 1)
            pos += (sdur[pos + s - 1] <= qb[k]) ? s : 0;
        if (wb[k] > 0.0f) {                        // ev[b]==1 <=> w_b>0
            lsum += wb[k] * ssuf[pos];
            lcnt += (ACHUNK - pos);
        }
    }

    // ---- wave shuffle-reduce (no barriers), then 4-way combine ----
#pragma unroll
    for (int d = 32; d > 0; d >>= 1) {
        lsum += __shfl_down(lsum, d, 64);
        lcnt += __shfl_down(lcnt, d, 64);
    }
    __shared__ float wsum[4];
    __shared__ int   wcnt[4];
    if (lane == 0) { wsum[wid] = lsum; wcnt[wid] = lcnt; }
    __syncthreads();
    if (threadIdx.x == 0) {
        psum[blockIdx.x] = (wsum[0] + wsum[1]) + (wsum[2] + wsum[3]);
        pcnt[blockIdx.x] = wcnt[0] + wcnt[1] + wcnt[2] + wcnt[3];
    }
}

__global__ void __launch_bounds__(TPB) finalize_kernel(const float* __restrict__ psum,
                                                       const int* __restrict__ pcnt,
                                                       float* __restrict__ out,
                                                       int nb) {
    __shared__ double    ds[TPB];
    __shared__ long long dc[TPB];
    double    ls = 0.0;
    long long lc = 0;
    for (int i = threadIdx.x; i < nb; i += TPB) {
        ls += (double)psum[i];
        lc += (long long)pcnt[i];
    }
    ds[threadIdx.x] = ls;
    dc[threadIdx.x] = lc;
    __syncthreads();
    for (int s = TPB / 2; s > 0; s >>= 1) {
        if (threadIdx.x < s) {
            ds[threadIdx.x] += ds[threadIdx.x + s];
            dc[threadIdx.x] += dc[threadIdx.x + s];
        }
        __syncthreads();
    }
    if (threadIdx.x == 0) {
        out[0] = (dc[0] > 0) ? (float)(ds[0] / (double)dc[0]) : 0.0f;
    }
}

extern "C" void kernel_launch(void* const* d_in, const int* in_sizes, int n_in,
                              void* d_out, int out_size, void* d_ws, size_t ws_size,
                              hipStream_t stream) {
    const float*  preds   = (const float*)d_in[0];
    const float2* targets = (const float2*)d_in[1];   // [n] of (dur, ev)
    float* out = (float*)d_out;
    int n = in_sizes[0];   // 8192

    int colGroups = n / (TPB * NB);                // 8
    int aChunks   = n / ACHUNK;                    // 128
    int nblocks   = colGroups * aChunks;           // 1024

    // ws layout: psum[nblocks] f32, pcnt[nblocks] i32
    float* psum = (float*)d_ws;
    int*   pcnt = (int*)(psum + nblocks);

    pair_fused<<<nblocks, TPB, 0, stream>>>(preds, targets, psum, pcnt, n);
    finalize_kernel<<<1, TPB, 0, stream>>>(psum, pcnt, out, nblocks);
}